// Round 5
// baseline (266.637 us; speedup 1.0000x reference)
//
#include <hip/hip_runtime.h>

// RefLocal: 5x5 windowed dot-product attention, fp32.
// B=8 H=96 W=96 C=192 V=96.
// R11 = R10 + off-LDS reduction + store-at-end + tree softmax.
//  - R10 post-mortem: 70us, no pipe saturated. LDS pipe ~47% busy, of
//    which ~7us is the shfl_xor butterfly (150 LDS shuffle ops/thread).
//  - Fix 1: xor1/xor2 reduction stages via DPP quad_perm (VALU pipe,
//    v_mov_dpp+add), xor4 via one ds_swizzle. LDS shuffle ops 150 -> 50.
//  - Fix 2: phase-2 outputs accumulate in registers (acc[3][2], +24 VGPR);
//    single store block after the last barrier. Previously the 2 stores
//    issued before each phase-2 barrier were drained by the barrier's
//    vmcnt(0) -> ~3 store-ack round trips on the critical path.
//  - Fix 3: softmax max/sum as log-depth trees (serial chain 24 -> 5).
//  - __launch_bounds__(256,4): live set ~110 < 128-VGPR occupancy step;
//    pin the 4-blocks/CU allocation. Tripwire: WRITE_SIZE must stay
//    exactly 27648 KB (any rise = spill, revert to (256,2)).

#define BATCH 8
#define HH 96
#define WW 96
#define CH 192
#define VV 96
#define KS 5
#define PAD 2
#define TH 8
#define TW 8
#define HT (TH + 2 * PAD) // 12
#define WT (TW + 2 * PAD) // 12
#define NPIX (HT * WT)    // 144
#define CHUNK 32          // channels staged per iteration
#define SPX 32            // LDS floats per halo pixel (contiguous, no pad)
#define BUFSZ (NPIX * SPX)   // 4608 floats = 18432 B per buffer
#define SSZ (2 * BUFSZ)      // 9216 floats = 36864 B
#define NVC (VV / CHUNK)     // 3 value chunks

#define DOT4(m, k) \
  ((m).x * (k).x + (m).y * (k).y + (m).z * (k).z + (m).w * (k).w)

// cross-lane add of lane^1 / lane^2 via DPP quad_perm (VALU pipe, no LDS)
#define DPPADD(x, CTRL)                                              \
  ((x) + __builtin_bit_cast(float, __builtin_amdgcn_update_dpp(      \
             0, __builtin_bit_cast(int, (x)), (CTRL), 0xF, 0xF, true)))
// cross-lane add of lane^4 via ds_swizzle BitMode (and=0x1F, xor=4)
#define SWZADD(x)                                                    \
  ((x) + __builtin_bit_cast(float, __builtin_amdgcn_ds_swizzle(      \
             __builtin_bit_cast(int, (x)), 0x101F)))

__device__ __forceinline__ void gload16(const float* g, float* l) {
  __builtin_amdgcn_global_load_lds(
      (const __attribute__((address_space(1))) float*)g,
      (__attribute__((address_space(3))) float*)l, 16, 0, 0);
}

__device__ __forceinline__ float tmax25(const float* v) {
  float t[13];
#pragma unroll
  for (int i = 0; i < 12; ++i) t[i] = fmaxf(v[2 * i], v[2 * i + 1]);
  t[12] = v[24];
  float u[7];
#pragma unroll
  for (int i = 0; i < 6; ++i) u[i] = fmaxf(t[2 * i], t[2 * i + 1]);
  u[6] = t[12];
  float w[4];
#pragma unroll
  for (int i = 0; i < 3; ++i) w[i] = fmaxf(u[2 * i], u[2 * i + 1]);
  w[3] = u[6];
  return fmaxf(fmaxf(w[0], w[1]), fmaxf(w[2], w[3]));
}

__device__ __forceinline__ float tsum25(const float* v) {
  float t[13];
#pragma unroll
  for (int i = 0; i < 12; ++i) t[i] = v[2 * i] + v[2 * i + 1];
  t[12] = v[24];
  float u[7];
#pragma unroll
  for (int i = 0; i < 6; ++i) u[i] = t[2 * i] + t[2 * i + 1];
  u[6] = t[12];
  float w[4];
#pragma unroll
  for (int i = 0; i < 3; ++i) w[i] = u[2 * i] + u[2 * i + 1];
  w[3] = u[6];
  return (w[0] + w[1]) + (w[2] + w[3]);
}

__global__ __launch_bounds__(256, 4) void reflocal_kernel(
    const float* __restrict__ qry, const float* __restrict__ key,
    const float* __restrict__ val, float* __restrict__ out) {
  // XCD swizzle: blockIdx round-robins across 8 XCDs; one image per XCD.
  int braw = blockIdx.x;
  int L = (braw & 7) * 144 + (braw >> 3); // gridDim.x == 1152
  int bb = L / 144;
  int t2 = L - bb * 144;
  int tyy = t2 / 12;
  int txx = t2 - tyy * 12;
  int h0 = tyy * TH, w0 = txx * TW;

  int tid = threadIdx.x;
  int s4 = (tid & 7) * 4;   // 4-channel sub-slice within the 32-ch chunk
  int pr = (tid >> 3) >> 2; // query row 0..7
  int pc = (tid >> 3) & 3;  // query col-pair 0..3
  int qx0 = 2 * pc;         // first query col (halo col of window j=0)
  int wv = tid >> 6;        // wave id 0..3

  __shared__ float s[SSZ];

  // ---- per-round staging bookkeeping ----
  // round r: wave wv covers pixels [32r+8wv, 32r+8wv+8); lane l>>3 picks
  // the pixel, lane l&7 the 16B quad (HW writes LDS at base + l*16B).
  int pidx[5]; // global pixel linear index; -1 = OOB zero slot; -2 = no slot
#pragma unroll
  for (int r = 0; r < 5; ++r) {
    int px = (tid >> 3) + 32 * r;
    if (px < NPIX) {
      int ry = px / WT, rx = px - ry * WT;
      int hh = h0 - PAD + ry, ww = w0 - PAD + rx;
      pidx[r] = ((unsigned)hh < HH && (unsigned)ww < WW)
                    ? (bb * HH + hh) * WW + ww
                    : -1;
    } else {
      pidx[r] = -2;
    }
  }

  // zero OOB slots ONCE in both buffers (masked gload lanes never write)
#pragma unroll
  for (int r = 0; r < 5; ++r) {
    if (pidx[r] == -1) {
      int px = (tid >> 3) + 32 * r;
      float4 z = make_float4(0.f, 0.f, 0.f, 0.f);
      *(float4*)(&s[px * SPX + s4]) = z;
      *(float4*)(&s[BUFSZ + px * SPX + s4]) = z;
    }
  }

  float lg0[25], lg1[25];
#pragma unroll
  for (int o = 0; o < 25; ++o) { lg0[o] = 0.f; lg1[o] = 0.f; }

  const float* qb0 =
      qry + (size_t)((bb * HH + h0 + pr) * WW + w0 + qx0) * CH;
  const float* qb1 = qb0 + CH; // adjacent column pixel

  // async stage: chunk [c0,c0+32) of src (row length rl) into buf
  auto stage = [&](float* buf, const float* src, int rl, int c0) {
#pragma unroll
    for (int r = 0; r < 5; ++r) {
      int pxs = 32 * r + 8 * wv; // wave-uniform first pixel of this issue
      if (pxs < NPIX) {
        if (pidx[r] >= 0)
          gload16(src + pidx[r] * rl + c0 + s4, buf + pxs * SPX);
      }
    }
  };

  float* const bufA = (float*)s;
  float* const bufB = (float*)s + BUFSZ;

  stage(bufA, key, CH, 0); // chunk 0 in flight

  // qry chunk-0 register prefetch
  float4 m0 = *(const float4*)(qb0 + s4);
  float4 m1 = *(const float4*)(qb1 + s4);

  // ---- Phase 1: partial logits, C in chunks of 32 ----
  for (int ci = 0; ci < CH / CHUNK; ++ci) {
    __syncthreads(); // drains vmcnt -> cur buffer complete for all waves
    float* cur = (ci & 1) ? bufB : bufA;
    float* nxt = (ci & 1) ? bufA : bufB;
    if (ci + 1 < CH / CHUNK)
      stage(nxt, key, CH, (ci + 1) * CHUNK);
    else
      stage(nxt, val, VV, 0); // V chunk 0 hides under last K compute+softmax

    // prefetch next chunk's qry into registers (lands during this compute)
    float4 mn0, mn1;
    if (ci + 1 < CH / CHUNK) {
      int cn = (ci + 1) * CHUNK + s4;
      mn0 = *(const float4*)(qb0 + cn);
      mn1 = *(const float4*)(qb1 + cn);
    }

#pragma unroll
    for (int i = 0; i < KS; ++i) {
      const float* sp = &cur[((pr + i) * WT + qx0) * SPX + s4];
      float4 kr[6];
#pragma unroll
      for (int u = 0; u < 6; ++u) kr[u] = *(const float4*)(sp + u * SPX);
#pragma unroll
      for (int j = 0; j < KS; ++j) {
        lg0[i * 5 + j] += DOT4(m0, kr[j]);
        lg1[i * 5 + j] += DOT4(m1, kr[j + 1]);
      }
    }
    m0 = mn0;
    m1 = mn1;
  }

  // ---- cross-slice logit reduction over lane bits 0..2:
  // xor1/xor2 on the VALU via DPP quad_perm; xor4 via one ds_swizzle.
#pragma unroll
  for (int o = 0; o < 25; ++o) {
    float a = lg0[o];
    a = DPPADD(a, 0xB1); // + lane^1  (quad_perm [1,0,3,2])
    a = DPPADD(a, 0x4E); // + lane^2  (quad_perm [2,3,0,1])
    lg0[o] = SWZADD(a);  // + lane^4
    float b = lg1[o];
    b = DPPADD(b, 0xB1);
    b = DPPADD(b, 0x4E);
    lg1[o] = SWZADD(b);
  }

  // ---- softmax over 25 (zero halo contributed logit 0 = TF SAME pad) ----
  {
    float mx = tmax25(lg0);
#pragma unroll
    for (int o = 0; o < 25; ++o) lg0[o] = __expf(lg0[o] - mx);
    float inv = 1.f / tsum25(lg0);
#pragma unroll
    for (int o = 0; o < 25; ++o) lg0[o] *= inv;
  }
  {
    float mx = tmax25(lg1);
#pragma unroll
    for (int o = 0; o < 25; ++o) lg1[o] = __expf(lg1[o] - mx);
    float inv = 1.f / tsum25(lg1);
#pragma unroll
    for (int o = 0; o < 25; ++o) lg1[o] *= inv;
  }

  // ---- Phase 2: values; outputs accumulate in registers, stored ONCE at
  // the end (no store-ack inside any barrier's vmcnt drain) ----
  float4 acc[NVC][2];
#pragma unroll
  for (int vi = 0; vi < NVC; ++vi) {
    __syncthreads(); // drains pending V-chunk loads
    float* cur = (vi & 1) ? bufB : bufA; // parity continues: V0 in bufA
    float* nxt = (vi & 1) ? bufA : bufB;
    if (vi + 1 < NVC) stage(nxt, val, VV, (vi + 1) * CHUNK);

    float4 a0 = make_float4(0.f, 0.f, 0.f, 0.f);
    float4 a1 = make_float4(0.f, 0.f, 0.f, 0.f);
#pragma unroll
    for (int i = 0; i < KS; ++i) {
      const float* sp = &cur[((pr + i) * WT + qx0) * SPX + s4];
      float4 vr[6];
#pragma unroll
      for (int u = 0; u < 6; ++u) vr[u] = *(const float4*)(sp + u * SPX);
#pragma unroll
      for (int j = 0; j < KS; ++j) {
        float w0a = lg0[i * 5 + j];
        float w1a = lg1[i * 5 + j];
        a0.x += w0a * vr[j].x;     a0.y += w0a * vr[j].y;
        a0.z += w0a * vr[j].z;     a0.w += w0a * vr[j].w;
        a1.x += w1a * vr[j + 1].x; a1.y += w1a * vr[j + 1].y;
        a1.z += w1a * vr[j + 1].z; a1.w += w1a * vr[j + 1].w;
      }
    }
    acc[vi][0] = a0;
    acc[vi][1] = a1;
  }

  // output: 8 lanes of an octet cover 128 contiguous bytes
  float* ob0 = out + (size_t)((bb * HH + h0 + pr) * WW + w0 + qx0) * VV;
  float* ob1 = ob0 + VV;
#pragma unroll
  for (int vi = 0; vi < NVC; ++vi) {
    *(float4*)(ob0 + vi * CHUNK + s4) = acc[vi][0];
    *(float4*)(ob1 + vi * CHUNK + s4) = acc[vi][1];
  }
}

extern "C" void kernel_launch(void* const* d_in, const int* in_sizes, int n_in,
                              void* d_out, int out_size, void* d_ws,
                              size_t ws_size, hipStream_t stream) {
  const float* qry = (const float*)d_in[0]; // main [B,H,W,C]
  const float* key = (const float*)d_in[1]; // ref  [B,H,W,C]
  const float* val = (const float*)d_in[2]; // ref_value [B,H,W,V]
  float* out = (float*)d_out;               // [B,H,W,V]

  dim3 grid(BATCH * (HH / TH) * (WW / TW)); // 1152
  dim3 block(256);
  reflocal_kernel<<<grid, block, 0, stream>>>(qry, key, val, out);
}

// Round 6
// 187.714 us; speedup vs baseline: 1.4204x; 1.4204x over previous
//
#include <hip/hip_runtime.h>

// RefLocal: 5x5 windowed dot-product attention, fp32.
// B=8 H=96 W=96 C=192 V=96.
// R12 = R10 + store-at-end ONLY (strict isolation after R11's spill).
//  - R11 post-mortem: bundling launch_bounds(256,4) + DPP reduction +
//    tree softmax demoted lg/acc to scratch (VGPR 64, +300MB scratch
//    traffic, 165us). Third launch-bounds poisoning (R7, R11). Reverted.
//  - Kept change: phase-2 outputs accumulate in acc[3][2] registers; one
//    store block after the last barrier. Mechanism: each phase-2
//    __syncthreads drains vmcnt(0), which previously included 2 output
//    store-acks (~300+cyc round trip x 3 barriers on the critical path).
//  - Launch bounds stay (256,2): allocator bound only; ~108-reg live set
//    lands under 128 -> 4 waves/SIMD naturally.
//  - Everything else IDENTICAL to R10 (70us, VGPR 84, clean traffic):
//    async global_load_lds double-buffer, pre-zeroed OOB slots, query
//    pairing, shfl_xor logit reduction, serial softmax.

#define BATCH 8
#define HH 96
#define WW 96
#define CH 192
#define VV 96
#define KS 5
#define PAD 2
#define TH 8
#define TW 8
#define HT (TH + 2 * PAD) // 12
#define WT (TW + 2 * PAD) // 12
#define NPIX (HT * WT)    // 144
#define CHUNK 32          // channels staged per iteration
#define SPX 32            // LDS floats per halo pixel (contiguous, no pad)
#define BUFSZ (NPIX * SPX)   // 4608 floats = 18432 B per buffer
#define SSZ (2 * BUFSZ)      // 9216 floats = 36864 B
#define NVC (VV / CHUNK)     // 3 value chunks

#define DOT4(m, k) \
  ((m).x * (k).x + (m).y * (k).y + (m).z * (k).z + (m).w * (k).w)

__device__ __forceinline__ void gload16(const float* g, float* l) {
  __builtin_amdgcn_global_load_lds(
      (const __attribute__((address_space(1))) float*)g,
      (__attribute__((address_space(3))) float*)l, 16, 0, 0);
}

__global__ __launch_bounds__(256, 2) void reflocal_kernel(
    const float* __restrict__ qry, const float* __restrict__ key,
    const float* __restrict__ val, float* __restrict__ out) {
  // XCD swizzle: blockIdx round-robins across 8 XCDs; one image per XCD.
  int braw = blockIdx.x;
  int L = (braw & 7) * 144 + (braw >> 3); // gridDim.x == 1152
  int bb = L / 144;
  int t2 = L - bb * 144;
  int tyy = t2 / 12;
  int txx = t2 - tyy * 12;
  int h0 = tyy * TH, w0 = txx * TW;

  int tid = threadIdx.x;
  int s4 = (tid & 7) * 4;   // 4-channel sub-slice within the 32-ch chunk
  int pr = (tid >> 3) >> 2; // query row 0..7
  int pc = (tid >> 3) & 3;  // query col-pair 0..3
  int qx0 = 2 * pc;         // first query col (halo col of window j=0)
  int wv = tid >> 6;        // wave id 0..3

  __shared__ float s[SSZ];

  // ---- per-round staging bookkeeping ----
  // round r: wave wv covers pixels [32r+8wv, 32r+8wv+8); lane l>>3 picks
  // the pixel, lane l&7 the 16B quad (HW writes LDS at base + l*16B).
  int pidx[5]; // global pixel linear index; -1 = OOB zero slot; -2 = no slot
#pragma unroll
  for (int r = 0; r < 5; ++r) {
    int px = (tid >> 3) + 32 * r;
    if (px < NPIX) {
      int ry = px / WT, rx = px - ry * WT;
      int hh = h0 - PAD + ry, ww = w0 - PAD + rx;
      pidx[r] = ((unsigned)hh < HH && (unsigned)ww < WW)
                    ? (bb * HH + hh) * WW + ww
                    : -1;
    } else {
      pidx[r] = -2;
    }
  }

  // zero OOB slots ONCE in both buffers (masked gload lanes never write)
#pragma unroll
  for (int r = 0; r < 5; ++r) {
    if (pidx[r] == -1) {
      int px = (tid >> 3) + 32 * r;
      float4 z = make_float4(0.f, 0.f, 0.f, 0.f);
      *(float4*)(&s[px * SPX + s4]) = z;
      *(float4*)(&s[BUFSZ + px * SPX + s4]) = z;
    }
  }

  float lg0[25], lg1[25];
#pragma unroll
  for (int o = 0; o < 25; ++o) { lg0[o] = 0.f; lg1[o] = 0.f; }

  const float* qb0 =
      qry + (size_t)((bb * HH + h0 + pr) * WW + w0 + qx0) * CH;
  const float* qb1 = qb0 + CH; // adjacent column pixel

  // async stage: chunk [c0,c0+32) of src (row length rl) into buf
  auto stage = [&](float* buf, const float* src, int rl, int c0) {
#pragma unroll
    for (int r = 0; r < 5; ++r) {
      int pxs = 32 * r + 8 * wv; // wave-uniform first pixel of this issue
      if (pxs < NPIX) {
        if (pidx[r] >= 0)
          gload16(src + pidx[r] * rl + c0 + s4, buf + pxs * SPX);
      }
    }
  };

  float* const bufA = (float*)s;
  float* const bufB = (float*)s + BUFSZ;

  stage(bufA, key, CH, 0); // chunk 0 in flight

  // qry chunk-0 register prefetch
  float4 m0 = *(const float4*)(qb0 + s4);
  float4 m1 = *(const float4*)(qb1 + s4);

  // ---- Phase 1: partial logits, C in chunks of 32 ----
  for (int ci = 0; ci < CH / CHUNK; ++ci) {
    __syncthreads(); // drains vmcnt -> cur buffer complete for all waves
    float* cur = (ci & 1) ? bufB : bufA;
    float* nxt = (ci & 1) ? bufA : bufB;
    if (ci + 1 < CH / CHUNK)
      stage(nxt, key, CH, (ci + 1) * CHUNK);
    else
      stage(nxt, val, VV, 0); // V chunk 0 hides under last K compute+softmax

    // prefetch next chunk's qry into registers (lands during this compute)
    float4 mn0, mn1;
    if (ci + 1 < CH / CHUNK) {
      int cn = (ci + 1) * CHUNK + s4;
      mn0 = *(const float4*)(qb0 + cn);
      mn1 = *(const float4*)(qb1 + cn);
    }

#pragma unroll
    for (int i = 0; i < KS; ++i) {
      const float* sp = &cur[((pr + i) * WT + qx0) * SPX + s4];
      float4 kr[6];
#pragma unroll
      for (int u = 0; u < 6; ++u) kr[u] = *(const float4*)(sp + u * SPX);
#pragma unroll
      for (int j = 0; j < KS; ++j) {
        lg0[i * 5 + j] += DOT4(m0, kr[j]);
        lg1[i * 5 + j] += DOT4(m1, kr[j + 1]);
      }
    }
    m0 = mn0;
    m1 = mn1;
  }

  // ---- cross-slice logit reduction: in-wave butterfly over lane bits 0..2
#pragma unroll
  for (int o = 0; o < 25; ++o) {
    lg0[o] += __shfl_xor(lg0[o], 1);
    lg0[o] += __shfl_xor(lg0[o], 2);
    lg0[o] += __shfl_xor(lg0[o], 4);
    lg1[o] += __shfl_xor(lg1[o], 1);
    lg1[o] += __shfl_xor(lg1[o], 2);
    lg1[o] += __shfl_xor(lg1[o], 4);
  }

  // ---- softmax over 25 (zero halo contributed logit 0 = TF SAME pad) ----
  {
    float mx = lg0[0];
#pragma unroll
    for (int o = 1; o < 25; ++o) mx = fmaxf(mx, lg0[o]);
    float sum = 0.f;
#pragma unroll
    for (int o = 0; o < 25; ++o) {
      lg0[o] = __expf(lg0[o] - mx);
      sum += lg0[o];
    }
    float inv = 1.f / sum;
#pragma unroll
    for (int o = 0; o < 25; ++o) lg0[o] *= inv;
  }
  {
    float mx = lg1[0];
#pragma unroll
    for (int o = 1; o < 25; ++o) mx = fmaxf(mx, lg1[o]);
    float sum = 0.f;
#pragma unroll
    for (int o = 0; o < 25; ++o) {
      lg1[o] = __expf(lg1[o] - mx);
      sum += lg1[o];
    }
    float inv = 1.f / sum;
#pragma unroll
    for (int o = 0; o < 25; ++o) lg1[o] *= inv;
  }

  // ---- Phase 2: values; outputs accumulate in registers, stored ONCE
  // after the last barrier (no store-ack in any barrier's vmcnt drain) ----
  float4 acc[NVC][2];
#pragma unroll
  for (int vi = 0; vi < NVC; ++vi) {
    __syncthreads(); // drains pending V-chunk loads
    float* cur = (vi & 1) ? bufB : bufA; // parity continues: V0 in bufA
    float* nxt = (vi & 1) ? bufA : bufB;
    if (vi + 1 < NVC) stage(nxt, val, VV, (vi + 1) * CHUNK);

    float4 a0 = make_float4(0.f, 0.f, 0.f, 0.f);
    float4 a1 = make_float4(0.f, 0.f, 0.f, 0.f);
#pragma unroll
    for (int i = 0; i < KS; ++i) {
      const float* sp = &cur[((pr + i) * WT + qx0) * SPX + s4];
      float4 vr[6];
#pragma unroll
      for (int u = 0; u < 6; ++u) vr[u] = *(const float4*)(sp + u * SPX);
#pragma unroll
      for (int j = 0; j < KS; ++j) {
        float w0a = lg0[i * 5 + j];
        float w1a = lg1[i * 5 + j];
        a0.x += w0a * vr[j].x;     a0.y += w0a * vr[j].y;
        a0.z += w0a * vr[j].z;     a0.w += w0a * vr[j].w;
        a1.x += w1a * vr[j + 1].x; a1.y += w1a * vr[j + 1].y;
        a1.z += w1a * vr[j + 1].z; a1.w += w1a * vr[j + 1].w;
      }
    }
    acc[vi][0] = a0;
    acc[vi][1] = a1;
  }

  // output: 8 lanes of an octet cover 128 contiguous bytes
  float* ob0 = out + (size_t)((bb * HH + h0 + pr) * WW + w0 + qx0) * VV;
  float* ob1 = ob0 + VV;
#pragma unroll
  for (int vi = 0; vi < NVC; ++vi) {
    *(float4*)(ob0 + vi * CHUNK + s4) = acc[vi][0];
    *(float4*)(ob1 + vi * CHUNK + s4) = acc[vi][1];
  }
}

extern "C" void kernel_launch(void* const* d_in, const int* in_sizes, int n_in,
                              void* d_out, int out_size, void* d_ws,
                              size_t ws_size, hipStream_t stream) {
  const float* qry = (const float*)d_in[0]; // main [B,H,W,C]
  const float* key = (const float*)d_in[1]; // ref  [B,H,W,C]
  const float* val = (const float*)d_in[2]; // ref_value [B,H,W,V]
  float* out = (float*)d_out;               // [B,H,W,V]

  dim3 grid(BATCH * (HH / TH) * (WW / TW)); // 1152
  dim3 block(256);
  reflocal_kernel<<<grid, block, 0, stream>>>(qry, key, val, out);
}